// Round 8
// baseline (145.842 us; speedup 1.0000x reference)
//
#include <hip/hip_runtime.h>
#include <hip/hip_bf16.h>

// ScaledDotProductAttention B=2,H=16,S=2048,D=64 causal, f32 in/out (probed).
// v8 = v7 with ONE change: complementary qb pairing on ADJACENT blocks.
// r7's occupancy (13.3% ~= half of balanced 25%) showed co-resident blocks
// are consecutive, not blk/blk+256 — so r7 put two EQUAL-work blocks on each
// CU (2-heavy CUs ran ~64 serial iters while 2-light CUs idled). Now
// blk=2i/2i+1 carry qb=15-h / h (sum = 34 iters) and share the same bh, so
// any consecutive-chunk assignment balances every CU exactly.
// Kernel body (sigma-permuted PV, LDS-shared tiles, no-max softmax) = r7.

typedef __attribute__((ext_vector_type(8))) short  s8v;   // 8 x bf16
typedef __attribute__((ext_vector_type(4))) short  s4v;   // 4 x bf16 (b64)
typedef __attribute__((ext_vector_type(4))) float  f4v;   // MFMA acc
typedef __attribute__((ext_vector_type(4))) unsigned int u4v;

#define SEQ 2048
#define DH  64
#define BHN 32
#define CSC 0.18033688f   // (1/sqrt(64)) * log2(e)

#if __has_builtin(__builtin_amdgcn_exp2f)
#define EXP2(x) __builtin_amdgcn_exp2f(x)
#else
#define EXP2(x) exp2f(x)
#endif

__device__ __forceinline__ unsigned short f2bf(float x) {
  union { float f; unsigned int u; } v; v.f = x;
  return (unsigned short)((v.u + 0x7fffu + ((v.u >> 16) & 1u)) >> 16);  // RNE
}
__device__ __forceinline__ float bf2f(unsigned short x) {
  union { unsigned int u; float f; } v; v.u = ((unsigned int)x) << 16;
  return v.f;
}
__device__ __forceinline__ int pack_bf2(float a, float b) {
  union { __hip_bfloat162 h; int i; } u;
  u.h = __float22bfloat162_rn(make_float2(a, b));   // a->low, b->high
  return u.i;
}
__device__ __forceinline__ bool probe_is_f32(const unsigned short* p) {
  const unsigned e = (p[threadIdx.x & 63] >> 7) & 0xFFu;
  return __ballot(e >= 0x89u) != 0ULL;
}
__device__ __forceinline__ s8v cvt8(const float* p) {
  float4 a = *(const float4*)p;
  float4 b = *(const float4*)(p + 4);
  s8v r;
  r[0] = (short)f2bf(a.x); r[1] = (short)f2bf(a.y);
  r[2] = (short)f2bf(a.z); r[3] = (short)f2bf(a.w);
  r[4] = (short)f2bf(b.x); r[5] = (short)f2bf(b.y);
  r[6] = (short)f2bf(b.z); r[7] = (short)f2bf(b.w);
  return r;
}
__device__ __forceinline__ s8v cvt8s(const float* p, float s) {
  float4 a = *(const float4*)p;
  float4 b = *(const float4*)(p + 4);
  s8v r;
  r[0] = (short)f2bf(a.x * s); r[1] = (short)f2bf(a.y * s);
  r[2] = (short)f2bf(a.z * s); r[3] = (short)f2bf(a.w * s);
  r[4] = (short)f2bf(b.x * s); r[5] = (short)f2bf(b.y * s);
  r[6] = (short)f2bf(b.z * s); r[7] = (short)f2bf(b.w * s);
  return r;
}

// ---- fused pre-pass: z=0 K->bf16 (same layout); z=1 V->Vt tiled transpose ----
__global__ __launch_bounds__(256) void prep_kernel(
    const void* __restrict__ Kv, const void* __restrict__ Vv,
    unsigned short* __restrict__ Kbf, unsigned short* __restrict__ Vt) {
  const int bh = blockIdx.y;
  const int s0 = blockIdx.x * 64;
  const int t  = threadIdx.x;
  if (blockIdx.z == 0) {
    const unsigned short* K16 = (const unsigned short*)Kv;
    const float*          KF  = (const float*)Kv;
    const bool isF32 = probe_is_f32(K16);
    const int sr = t >> 2, c0 = (t & 3) * 16;
    const size_t base = ((size_t)(bh * SEQ + s0 + sr)) * DH + c0;
    s8v a0, a1;
    if (!isF32) { a0 = *(const s8v*)(K16 + base); a1 = *(const s8v*)(K16 + base + 8); }
    else        { a0 = cvt8(KF + base);           a1 = cvt8(KF + base + 8); }
    *(s8v*)(Kbf + base)     = a0;
    *(s8v*)(Kbf + base + 8) = a1;
  } else {
    __shared__ __align__(16) unsigned short T[64][72];
    const unsigned short* V16 = (const unsigned short*)Vv;
    const float*          VF  = (const float*)Vv;
    const bool isF32 = probe_is_f32(V16);
    {
      const int sr = t >> 2, c0 = (t & 3) * 16;
      const size_t base = ((size_t)(bh * SEQ + s0 + sr)) * DH + c0;
      s8v a0, a1;
      if (!isF32) { a0 = *(const s8v*)(V16 + base); a1 = *(const s8v*)(V16 + base + 8); }
      else        { a0 = cvt8(VF + base);           a1 = cvt8(VF + base + 8); }
      *(s8v*)&T[sr][c0]     = a0;
      *(s8v*)&T[sr][c0 + 8] = a1;
    }
    __syncthreads();
    {
      const int d  = t & 63;
      const int sb = (t >> 6) * 16;
      unsigned int wb[8];
#pragma unroll
      for (int j = 0; j < 8; ++j) {
        unsigned int lo = T[sb + 2 * j][d];
        unsigned int hi = T[sb + 2 * j + 1][d];
        wb[j] = lo | (hi << 16);
      }
      unsigned short* dst = Vt + (size_t)bh * SEQ * DH + (size_t)s0 * 64 + d * 64 + sb;
      u4v q0 = { wb[0], wb[1], wb[2], wb[3] };
      u4v q1 = { wb[4], wb[5], wb[6], wb[7] };
      *(u4v*)dst       = q0;
      *(u4v*)(dst + 8) = q1;
    }
  }
}

// ---- main: flash attention, sigma-permuted PV, LDS-shared K/V tiles ----
__global__ __launch_bounds__(256, 2) void attn_kernel(
    const void* __restrict__ Qv, const unsigned short* __restrict__ Kbf,
    const unsigned short* __restrict__ Vt, void* __restrict__ Outv) {
  __shared__ __align__(16) unsigned short Ks[2][64][72];   // [buf][key][d]
  __shared__ __align__(16) unsigned short Vs[2][64][72];   // [buf][d][key]

  const unsigned short* Q16 = (const unsigned short*)Qv;
  const float*          QF  = (const float*)Qv;
  const bool isF32 = probe_is_f32(Q16);

  // ADJACENT complementary pairing: blk=2i -> qb=15-h (heavy), blk=2i+1 ->
  // qb=h (light); pair shares bh. Consecutive-chunk CU assignment => every
  // CU gets 34 iters per pair.
  const int blk     = blockIdx.x;
  const int pairIdx = blk >> 1;          // 0..255
  const int side    = blk & 1;
  const int h       = pairIdx >> 5;      // 0..7
  const int bj      = pairIdx & 31;
  const int bh      = (bj & 7) * 4 + (bj >> 3);   // XCD-clustered K/V reuse
  const int qb      = side ? h : (15 - h);

  const int tid  = threadIdx.x;
  const int w    = tid >> 6;
  const int lane = tid & 63;
  const int quad = lane >> 4;
  const int c16  = lane & 15;
  const int q0   = qb * 128 + w * 32;                  // this wave's 32 q-rows

  const size_t bh_off = (size_t)bh * SEQ * DH;
  const unsigned short* Kb = Kbf + bh_off;
  const unsigned short* Vb = Vt  + bh_off;

  // Q fragments, prescaled by CSC (B-operand layout == A-operand layout)
  s8v aq[2][2];
#pragma unroll
  for (int mr = 0; mr < 2; ++mr)
#pragma unroll
    for (int kc = 0; kc < 2; ++kc) {
      const size_t idx = bh_off + (size_t)(q0 + mr * 16 + c16) * DH + kc * 32 + quad * 8;
      if (isF32) aq[mr][kc] = cvt8s(QF + idx, CSC);
      else {
        s8v a = *(const s8v*)(Q16 + idx);
#pragma unroll
        for (int t = 0; t < 8; ++t)
          a[t] = (short)f2bf(bf2f((unsigned short)a[t]) * CSC);
        aq[mr][kc] = a;
      }
    }

  f4v o[2][4];
  float l[2] = {0.f, 0.f};
#pragma unroll
  for (int mr = 0; mr < 2; ++mr)
#pragma unroll
    for (int i = 0; i < 4; ++i) { f4v z = {0.f, 0.f, 0.f, 0.f}; o[mr][i] = z; }

  const int ntiles = 2 * qb + 2;

  // staging: thread -> 32B of K row and 32B of V row (tile stride 64*DH shorts)
  const int srow = tid >> 2;
  const int scol = (tid & 3) * 16;
  const unsigned short* Kst = Kb + (size_t)srow * DH + scol;
  const unsigned short* Vst = Vb + (size_t)srow * 64 + scol;

  { // prologue: stage tile 0 into buf 0
    s8v k0 = *(const s8v*)(Kst), k1 = *(const s8v*)(Kst + 8);
    s8v v0 = *(const s8v*)(Vst), v1 = *(const s8v*)(Vst + 8);
    *(s8v*)&Ks[0][srow][scol]     = k0;
    *(s8v*)&Ks[0][srow][scol + 8] = k1;
    *(s8v*)&Vs[0][srow][scol]     = v0;
    *(s8v*)&Vs[0][srow][scol + 8] = v1;
  }
  __syncthreads();

  for (int kt = 0; kt < ntiles; ++kt) {
    const int cb = kt & 1, nb = cb ^ 1;
    // issue next tile's global loads now; ds_write after compute
    const size_t koff = (size_t)((kt + 1 < ntiles) ? kt + 1 : 0) * (64 * DH);
    s8v nk0 = *(const s8v*)(Kst + koff), nk1 = *(const s8v*)(Kst + koff + 8);
    s8v nv0 = *(const s8v*)(Vst + koff), nv1 = *(const s8v*)(Vst + koff + 8);

    if (kt * 64 <= q0 + 31) {   // wave-uniform: any of my rows attend this tile
      // K A-frags from LDS
      s8v kb[4][2];
#pragma unroll
      for (int nt = 0; nt < 4; ++nt) {
        kb[nt][0] = *(const s8v*)&Ks[cb][nt * 16 + c16][quad * 8];
        kb[nt][1] = *(const s8v*)&Ks[cb][nt * 16 + c16][32 + quad * 8];
      }
      // V B-frags via sigma: keys kc*32 + {4*quad..+3, 16+4*quad..+3}
      s8v vb[4][2];
#pragma unroll
      for (int dt = 0; dt < 4; ++dt)
#pragma unroll
        for (int kc = 0; kc < 2; ++kc) {
          const unsigned short* vr = &Vs[cb][dt * 16 + c16][kc * 32 + quad * 4];
          union { s4v h[2]; s8v v; } uv;
          uv.h[0] = *(const s4v*)(vr);        // keys +0..3   (j=0..3)
          uv.h[1] = *(const s4v*)(vr + 16);   // keys +16..19 (j=4..7)
          vb[dt][kc] = uv.v;
        }

#pragma unroll
      for (int mr = 0; mr < 2; ++mr) {
        const int rbase = q0 + mr * 16;
        if (kt * 64 > rbase + 15) continue;   // wave-uniform per mr
        // S^T = K·Q^T: lane holds query=c16, keys=nt*16+quad*4+r
        float p[4][4];
#pragma unroll
        for (int nt = 0; nt < 4; ++nt) {
          f4v acc = {0.f, 0.f, 0.f, 0.f};
          acc = __builtin_amdgcn_mfma_f32_16x16x32_bf16(kb[nt][0], aq[mr][0], acc, 0, 0, 0);
          acc = __builtin_amdgcn_mfma_f32_16x16x32_bf16(kb[nt][1], aq[mr][1], acc, 0, 0, 0);
#pragma unroll
          for (int r = 0; r < 4; ++r) p[nt][r] = EXP2(acc[r]);  // no-max: f32-safe
        }
        if (kt * 64 + 63 > rbase) {  // diagonal tile: zero masked probs
          const int qmk = rbase + c16 - kt * 64 - quad * 4;
#pragma unroll
          for (int nt = 0; nt < 4; ++nt)
#pragma unroll
            for (int r = 0; r < 4; ++r)
              if (nt * 16 + r > qmk) p[nt][r] = 0.f;
        }
        float s = 0.f;
#pragma unroll
        for (int nt = 0; nt < 4; ++nt)
          s += (p[nt][0] + p[nt][1]) + (p[nt][2] + p[nt][3]);
        l[mr] += s;
        // P A-frags: pure in-lane pack (sigma ordering), zero cross-lane ops
#pragma unroll
        for (int kc = 0; kc < 2; ++kc) {
          union { int d[4]; s8v v; } u;
          u.d[0] = pack_bf2(p[2 * kc][0],     p[2 * kc][1]);
          u.d[1] = pack_bf2(p[2 * kc][2],     p[2 * kc][3]);
          u.d[2] = pack_bf2(p[2 * kc + 1][0], p[2 * kc + 1][1]);
          u.d[3] = pack_bf2(p[2 * kc + 1][2], p[2 * kc + 1][3]);
          // PV: O += P·V (k-permutation sigma shared by A and B)
#pragma unroll
          for (int dt = 0; dt < 4; ++dt)
            o[mr][dt] = __builtin_amdgcn_mfma_f32_16x16x32_bf16(u.v, vb[dt][kc], o[mr][dt], 0, 0, 0);
        }
      }
    }
    // stage next tile (other buffer) and barrier once
    *(s8v*)&Ks[nb][srow][scol]     = nk0;
    *(s8v*)&Ks[nb][srow][scol + 8] = nk1;
    *(s8v*)&Vs[nb][srow][scol]     = nv0;
    *(s8v*)&Vs[nb][srow][scol + 8] = nv1;
    __syncthreads();
  }

  // ---- epilogue: wave-local ----
#pragma unroll
  for (int mr = 0; mr < 2; ++mr) {
    float lv = l[mr];
    lv += __shfl_xor(lv, 16);
    lv += __shfl_xor(lv, 32);     // l(query=c16), replicated over quads
    union { float f; int i; } lu; lu.f = lv;
    float invr[4];
#pragma unroll
    for (int rr = 0; rr < 4; ++rr) {
      union { int i; float f; } tf;
      tf.i = __builtin_amdgcn_ds_bpermute(4 * (quad * 4 + rr), lu.i);
      invr[rr] = 1.0f / tf.f;     // l for my output row quad*4+rr
    }
    if (isF32) {
      float* OF = (float*)Outv;
#pragma unroll
      for (int rr = 0; rr < 4; ++rr) {
        const size_t rb = bh_off + (size_t)(q0 + mr * 16 + quad * 4 + rr) * DH + c16;
#pragma unroll
        for (int dt = 0; dt < 4; ++dt)
          OF[rb + dt * 16] = o[mr][dt][rr] * invr[rr];
      }
    } else {
      unsigned short* O16 = (unsigned short*)Outv;
#pragma unroll
      for (int rr = 0; rr < 4; ++rr) {
        const size_t rb = bh_off + (size_t)(q0 + mr * 16 + quad * 4 + rr) * DH + c16;
#pragma unroll
        for (int dt = 0; dt < 4; ++dt)
          O16[rb + dt * 16] = f2bf(o[mr][dt][rr] * invr[rr]);
      }
    }
  }
}

extern "C" void kernel_launch(void* const* d_in, const int* in_sizes, int n_in,
                              void* d_out, int out_size, void* d_ws, size_t ws_size,
                              hipStream_t stream) {
  const void* Q = d_in[0];
  const void* K = d_in[1];
  const void* V = d_in[2];
  unsigned short* Kbf = (unsigned short*)d_ws;                     // 8.39 MB
  unsigned short* Vt  = Kbf + (size_t)BHN * SEQ * DH;              // 8.39 MB

  dim3 g1(SEQ / 64, BHN, 2);
  prep_kernel<<<g1, 256, 0, stream>>>(K, V, Kbf, Vt);
  attn_kernel<<<dim3(512), 256, 0, stream>>>(Q, Kbf, Vt, d_out);
}

// Round 9
// 142.853 us; speedup vs baseline: 1.0209x; 1.0209x over previous
//
#include <hip/hip_runtime.h>
#include <hip/hip_bf16.h>

// ScaledDotProductAttention B=2,H=16,S=2048,D=64 causal, f32 in/out (probed).
// v9: concurrency fix. r7/r8 showed balance isn't the limiter; wall = serial
// per-iter latency x only 2 blocks/CU. Now 64 q-rows/block -> 1024 blocks =
// 4 blocks/CU (16 waves/CU), LDS 4x36KB=144<=160KB. Every wave computes every
// tile (16 rows/wave, no mr loop). Balance under {blk,+256,+512,+768}
// co-residency: qb quad {7-a, 8+a, 23-a, 24+a} sums 66 iters/CU; bh =
// (blk&7)*4+((blk>>3)&3) keeps 4 bh per XCD L2. Body math = r7 (sigma-
// permuted PV, no-max softmax, deferred l, CSC folded into Q).

typedef __attribute__((ext_vector_type(8))) short  s8v;   // 8 x bf16
typedef __attribute__((ext_vector_type(4))) short  s4v;   // 4 x bf16 (b64)
typedef __attribute__((ext_vector_type(4))) float  f4v;   // MFMA acc
typedef __attribute__((ext_vector_type(4))) unsigned int u4v;

#define SEQ 2048
#define DH  64
#define BHN 32
#define CSC 0.18033688f   // (1/sqrt(64)) * log2(e)

#if __has_builtin(__builtin_amdgcn_exp2f)
#define EXP2(x) __builtin_amdgcn_exp2f(x)
#else
#define EXP2(x) exp2f(x)
#endif

__device__ __forceinline__ unsigned short f2bf(float x) {
  union { float f; unsigned int u; } v; v.f = x;
  return (unsigned short)((v.u + 0x7fffu + ((v.u >> 16) & 1u)) >> 16);  // RNE
}
__device__ __forceinline__ float bf2f(unsigned short x) {
  union { unsigned int u; float f; } v; v.u = ((unsigned int)x) << 16;
  return v.f;
}
__device__ __forceinline__ int pack_bf2(float a, float b) {
  union { __hip_bfloat162 h; int i; } u;
  u.h = __float22bfloat162_rn(make_float2(a, b));   // a->low, b->high
  return u.i;
}
__device__ __forceinline__ bool probe_is_f32(const unsigned short* p) {
  const unsigned e = (p[threadIdx.x & 63] >> 7) & 0xFFu;
  return __ballot(e >= 0x89u) != 0ULL;
}
__device__ __forceinline__ s8v cvt8(const float* p) {
  float4 a = *(const float4*)p;
  float4 b = *(const float4*)(p + 4);
  s8v r;
  r[0] = (short)f2bf(a.x); r[1] = (short)f2bf(a.y);
  r[2] = (short)f2bf(a.z); r[3] = (short)f2bf(a.w);
  r[4] = (short)f2bf(b.x); r[5] = (short)f2bf(b.y);
  r[6] = (short)f2bf(b.z); r[7] = (short)f2bf(b.w);
  return r;
}
__device__ __forceinline__ s8v cvt8s(const float* p, float s) {
  float4 a = *(const float4*)p;
  float4 b = *(const float4*)(p + 4);
  s8v r;
  r[0] = (short)f2bf(a.x * s); r[1] = (short)f2bf(a.y * s);
  r[2] = (short)f2bf(a.z * s); r[3] = (short)f2bf(a.w * s);
  r[4] = (short)f2bf(b.x * s); r[5] = (short)f2bf(b.y * s);
  r[6] = (short)f2bf(b.z * s); r[7] = (short)f2bf(b.w * s);
  return r;
}

// ---- fused pre-pass: z=0 K->bf16 (same layout); z=1 V->Vt tiled transpose ----
__global__ __launch_bounds__(256) void prep_kernel(
    const void* __restrict__ Kv, const void* __restrict__ Vv,
    unsigned short* __restrict__ Kbf, unsigned short* __restrict__ Vt) {
  const int bh = blockIdx.y;
  const int s0 = blockIdx.x * 64;
  const int t  = threadIdx.x;
  if (blockIdx.z == 0) {
    const unsigned short* K16 = (const unsigned short*)Kv;
    const float*          KF  = (const float*)Kv;
    const bool isF32 = probe_is_f32(K16);
    const int sr = t >> 2, c0 = (t & 3) * 16;
    const size_t base = ((size_t)(bh * SEQ + s0 + sr)) * DH + c0;
    s8v a0, a1;
    if (!isF32) { a0 = *(const s8v*)(K16 + base); a1 = *(const s8v*)(K16 + base + 8); }
    else        { a0 = cvt8(KF + base);           a1 = cvt8(KF + base + 8); }
    *(s8v*)(Kbf + base)     = a0;
    *(s8v*)(Kbf + base + 8) = a1;
  } else {
    __shared__ __align__(16) unsigned short T[64][72];
    const unsigned short* V16 = (const unsigned short*)Vv;
    const float*          VF  = (const float*)Vv;
    const bool isF32 = probe_is_f32(V16);
    {
      const int sr = t >> 2, c0 = (t & 3) * 16;
      const size_t base = ((size_t)(bh * SEQ + s0 + sr)) * DH + c0;
      s8v a0, a1;
      if (!isF32) { a0 = *(const s8v*)(V16 + base); a1 = *(const s8v*)(V16 + base + 8); }
      else        { a0 = cvt8(VF + base);           a1 = cvt8(VF + base + 8); }
      *(s8v*)&T[sr][c0]     = a0;
      *(s8v*)&T[sr][c0 + 8] = a1;
    }
    __syncthreads();
    {
      const int d  = t & 63;
      const int sb = (t >> 6) * 16;
      unsigned int wb[8];
#pragma unroll
      for (int j = 0; j < 8; ++j) {
        unsigned int lo = T[sb + 2 * j][d];
        unsigned int hi = T[sb + 2 * j + 1][d];
        wb[j] = lo | (hi << 16);
      }
      unsigned short* dst = Vt + (size_t)bh * SEQ * DH + (size_t)s0 * 64 + d * 64 + sb;
      u4v q0 = { wb[0], wb[1], wb[2], wb[3] };
      u4v q1 = { wb[4], wb[5], wb[6], wb[7] };
      *(u4v*)dst       = q0;
      *(u4v*)(dst + 8) = q1;
    }
  }
}

// ---- main: flash attention, 64 q-rows/block, 4 blocks/CU ----
__global__ __launch_bounds__(256, 4) void attn_kernel(
    const void* __restrict__ Qv, const unsigned short* __restrict__ Kbf,
    const unsigned short* __restrict__ Vt, void* __restrict__ Outv) {
  __shared__ __align__(16) unsigned short Ks[2][64][72];   // [buf][key][d]
  __shared__ __align__(16) unsigned short Vs[2][64][72];   // [buf][d][key]

  const unsigned short* Q16 = (const unsigned short*)Qv;
  const float*          QF  = (const float*)Qv;
  const bool isF32 = probe_is_f32(Q16);

  // decode: xcd=blk&7, c=(blk>>3)&31, a=(blk>>5)&7, b=blk>>8
  const int blk = blockIdx.x;
  const int bh  = (blk & 7) * 4 + ((blk >> 3) & 3);   // 4 bh per XCD
  const int a   = (blk >> 5) & 7;
  const int bsl = blk >> 8;                            // 0..3
  const int qb  = (bsl == 0) ? (7 - a) : (bsl == 1) ? (8 + a)
                : (bsl == 2) ? (23 - a) : (24 + a);    // CU quad sums 66 iters

  const int tid  = threadIdx.x;
  const int w    = tid >> 6;
  const int lane = tid & 63;
  const int quad = lane >> 4;
  const int c16  = lane & 15;
  const int q0   = qb * 64 + w * 16;                   // this wave's 16 q-rows

  const size_t bh_off = (size_t)bh * SEQ * DH;
  const unsigned short* Kb = Kbf + bh_off;
  const unsigned short* Vb = Vt  + bh_off;

  // Q fragment (B-operand layout == A-operand layout), prescaled by CSC
  s8v aq[2];
#pragma unroll
  for (int kc = 0; kc < 2; ++kc) {
    const size_t idx = bh_off + (size_t)(q0 + c16) * DH + kc * 32 + quad * 8;
    if (isF32) aq[kc] = cvt8s(QF + idx, CSC);
    else {
      s8v aa = *(const s8v*)(Q16 + idx);
#pragma unroll
      for (int t = 0; t < 8; ++t)
        aa[t] = (short)f2bf(bf2f((unsigned short)aa[t]) * CSC);
      aq[kc] = aa;
    }
  }

  f4v o[4];
  float l = 0.f;
#pragma unroll
  for (int i = 0; i < 4; ++i) { f4v z = {0.f, 0.f, 0.f, 0.f}; o[i] = z; }

  const int ntiles = qb + 1;

  // staging: thread -> 32B of K row and 32B of V row (tile stride 64*DH shorts)
  const int srow = tid >> 2;
  const int scol = (tid & 3) * 16;
  const unsigned short* Kst = Kb + (size_t)srow * DH + scol;
  const unsigned short* Vst = Vb + (size_t)srow * 64 + scol;

  { // prologue: stage tile 0 into buf 0
    s8v k0 = *(const s8v*)(Kst), k1 = *(const s8v*)(Kst + 8);
    s8v v0 = *(const s8v*)(Vst), v1 = *(const s8v*)(Vst + 8);
    *(s8v*)&Ks[0][srow][scol]     = k0;
    *(s8v*)&Ks[0][srow][scol + 8] = k1;
    *(s8v*)&Vs[0][srow][scol]     = v0;
    *(s8v*)&Vs[0][srow][scol + 8] = v1;
  }
  __syncthreads();

  for (int kt = 0; kt < ntiles; ++kt) {
    const int cb = kt & 1, nb = cb ^ 1;
    // issue next tile's global loads now; ds_write after compute
    const size_t koff = (size_t)((kt + 1 < ntiles) ? kt + 1 : 0) * (64 * DH);
    s8v nk0 = *(const s8v*)(Kst + koff), nk1 = *(const s8v*)(Kst + koff + 8);
    s8v nv0 = *(const s8v*)(Vst + koff), nv1 = *(const s8v*)(Vst + koff + 8);

    // K A-frags from LDS
    s8v kb[4][2];
#pragma unroll
    for (int nt = 0; nt < 4; ++nt) {
      kb[nt][0] = *(const s8v*)&Ks[cb][nt * 16 + c16][quad * 8];
      kb[nt][1] = *(const s8v*)&Ks[cb][nt * 16 + c16][32 + quad * 8];
    }
    // V B-frags via sigma: keys kc*32 + {4*quad..+3, 16+4*quad..+3}
    s8v vb[4][2];
#pragma unroll
    for (int dt = 0; dt < 4; ++dt)
#pragma unroll
      for (int kc = 0; kc < 2; ++kc) {
        const unsigned short* vr = &Vs[cb][dt * 16 + c16][kc * 32 + quad * 4];
        union { s4v h[2]; s8v v; } uv;
        uv.h[0] = *(const s4v*)(vr);        // keys +0..3   (j=0..3)
        uv.h[1] = *(const s4v*)(vr + 16);   // keys +16..19 (j=4..7)
        vb[dt][kc] = uv.v;
      }

    // S^T = K·Q^T: lane holds query=c16, keys=nt*16+quad*4+r
    float p[4][4];
#pragma unroll
    for (int nt = 0; nt < 4; ++nt) {
      f4v acc = {0.f, 0.f, 0.f, 0.f};
      acc = __builtin_amdgcn_mfma_f32_16x16x32_bf16(kb[nt][0], aq[0], acc, 0, 0, 0);
      acc = __builtin_amdgcn_mfma_f32_16x16x32_bf16(kb[nt][1], aq[1], acc, 0, 0, 0);
#pragma unroll
      for (int r = 0; r < 4; ++r) p[nt][r] = EXP2(acc[r]);  // no-max: f32-safe
    }
    if (kt * 64 + 63 > q0) {  // diagonal tile: zero masked probs
      const int qmk = q0 + c16 - kt * 64 - quad * 4;
#pragma unroll
      for (int nt = 0; nt < 4; ++nt)
#pragma unroll
        for (int r = 0; r < 4; ++r)
          if (nt * 16 + r > qmk) p[nt][r] = 0.f;
    }
    float s = 0.f;
#pragma unroll
    for (int nt = 0; nt < 4; ++nt)
      s += (p[nt][0] + p[nt][1]) + (p[nt][2] + p[nt][3]);
    l += s;
    // P A-frags: pure in-lane pack (sigma ordering); PV with shared sigma
#pragma unroll
    for (int kc = 0; kc < 2; ++kc) {
      union { int d[4]; s8v v; } u;
      u.d[0] = pack_bf2(p[2 * kc][0],     p[2 * kc][1]);
      u.d[1] = pack_bf2(p[2 * kc][2],     p[2 * kc][3]);
      u.d[2] = pack_bf2(p[2 * kc + 1][0], p[2 * kc + 1][1]);
      u.d[3] = pack_bf2(p[2 * kc + 1][2], p[2 * kc + 1][3]);
#pragma unroll
      for (int dt = 0; dt < 4; ++dt)
        o[dt] = __builtin_amdgcn_mfma_f32_16x16x32_bf16(u.v, vb[dt][kc], o[dt], 0, 0, 0);
    }

    // stage next tile (other buffer) and barrier once
    *(s8v*)&Ks[nb][srow][scol]     = nk0;
    *(s8v*)&Ks[nb][srow][scol + 8] = nk1;
    *(s8v*)&Vs[nb][srow][scol]     = nv0;
    *(s8v*)&Vs[nb][srow][scol + 8] = nv1;
    __syncthreads();
  }

  // ---- epilogue: wave-local ----
  {
    float lv = l;
    lv += __shfl_xor(lv, 16);
    lv += __shfl_xor(lv, 32);     // l(query=c16), replicated over quads
    union { float f; int i; } lu; lu.f = lv;
    float invr[4];
#pragma unroll
    for (int rr = 0; rr < 4; ++rr) {
      union { int i; float f; } tf;
      tf.i = __builtin_amdgcn_ds_bpermute(4 * (quad * 4 + rr), lu.i);
      invr[rr] = 1.0f / tf.f;     // l for my output row quad*4+rr
    }
    if (isF32) {
      float* OF = (float*)Outv;
#pragma unroll
      for (int rr = 0; rr < 4; ++rr) {
        const size_t rb = bh_off + (size_t)(q0 + quad * 4 + rr) * DH + c16;
#pragma unroll
        for (int dt = 0; dt < 4; ++dt)
          OF[rb + dt * 16] = o[dt][rr] * invr[rr];
      }
    } else {
      unsigned short* O16 = (unsigned short*)Outv;
#pragma unroll
      for (int rr = 0; rr < 4; ++rr) {
        const size_t rb = bh_off + (size_t)(q0 + quad * 4 + rr) * DH + c16;
#pragma unroll
        for (int dt = 0; dt < 4; ++dt)
          O16[rb + dt * 16] = f2bf(o[dt][rr] * invr[rr]);
      }
    }
  }
}

extern "C" void kernel_launch(void* const* d_in, const int* in_sizes, int n_in,
                              void* d_out, int out_size, void* d_ws, size_t ws_size,
                              hipStream_t stream) {
  const void* Q = d_in[0];
  const void* K = d_in[1];
  const void* V = d_in[2];
  unsigned short* Kbf = (unsigned short*)d_ws;                     // 8.39 MB
  unsigned short* Vt  = Kbf + (size_t)BHN * SEQ * DH;              // 8.39 MB

  dim3 g1(SEQ / 64, BHN, 2);
  prep_kernel<<<g1, 256, 0, stream>>>(K, V, Kbf, Vt);
  attn_kernel<<<dim3(1024), 256, 0, stream>>>(Q, Kbf, Vt, d_out);
}